// Round 3
// baseline (493.110 us; speedup 1.0000x reference)
//
#include <hip/hip_runtime.h>
#include <hip/hip_bf16.h>

#define DEV __device__ __forceinline__

typedef unsigned short u16;
typedef unsigned int u32;
typedef __bf16 bf16x8 __attribute__((ext_vector_type(8)));
typedef float f32x4 __attribute__((ext_vector_type(4)));

static constexpr int S   = 2048;
static constexpr int D   = 1024;
static constexpr int H   = 16;
static constexpr int Dh  = 64;
static constexpr int B_  = 4;
static constexpr int M   = B_ * S;   // 8192 tokens

DEV u16 f2bf(float f) {
    __hip_bfloat16 h = __float2bfloat16(f);
    union { __hip_bfloat16 h; u16 u; } cv; cv.h = h; return cv.u;
}
DEV f32x4 mfma16(bf16x8 a, bf16x8 b, f32x4 c) {
    return __builtin_amdgcn_mfma_f32_16x16x32_bf16(a, b, c, 0, 0, 0);
}
// load 8 contiguous fp32, round to 8 bf16 (two float4 vector loads)
DEV bf16x8 ld8f(const float* p) {
    const f32x4* q = reinterpret_cast<const f32x4*>(p);
    f32x4 a = q[0], b = q[1];
    union { u16 u[8]; bf16x8 v; } r;
    r.u[0] = f2bf(a[0]); r.u[1] = f2bf(a[1]); r.u[2] = f2bf(a[2]); r.u[3] = f2bf(a[3]);
    r.u[4] = f2bf(b[0]); r.u[5] = f2bf(b[1]); r.u[6] = f2bf(b[2]); r.u[7] = f2bf(b[3]);
    return r.v;
}

// ---------------------------------------------------------------------------
// Transpose + bf16-convert the 4 fp32 weight matrices [K][N] -> bf16 [N][K]
// ---------------------------------------------------------------------------
__global__ __launch_bounds__(256) void transpose_w(
    const float* __restrict__ Wq, const float* __restrict__ Wk,
    const float* __restrict__ Wv, const float* __restrict__ Wo,
    u16* __restrict__ WT)
{
    const float* src = blockIdx.z == 0 ? Wq : blockIdx.z == 1 ? Wk
                     : blockIdx.z == 2 ? Wv : Wo;
    u16* dst = WT + (size_t)blockIdx.z * D * D;
    __shared__ u16 T[64 * 72];
    const int k0 = blockIdx.x * 64, n0 = blockIdx.y * 64;
    const int tid = threadIdx.x;
    for (int c = tid; c < 512; c += 256) {
        int r = c >> 3, cc = (c & 7) << 3;
        *reinterpret_cast<bf16x8*>(&T[r * 72 + cc]) =
            ld8f(&src[(size_t)(k0 + r) * D + n0 + cc]);
    }
    __syncthreads();
    for (int c = tid; c < 512; c += 256) {
        int r = c >> 3, cc = (c & 7) << 3;   // r: n-row of dst tile, cc: k-chunk
        u16 tmp[8];
        #pragma unroll
        for (int i = 0; i < 8; ++i) tmp[i] = T[(cc + i) * 72 + r];
        *reinterpret_cast<bf16x8*>(&dst[(size_t)(n0 + r) * D + k0 + cc]) =
            *reinterpret_cast<const bf16x8*>(tmp);
    }
}

// ---------------------------------------------------------------------------
// Fused QKV GEMM: fp32 x [8192x1024] @ bf16 W^T -> bf16 Q/K/V [b*H+h][s][dh].
// 64x64 block tile, BK=32, 4 waves 2x2, each wave 32x32 (2x2 MFMA tiles).
// ---------------------------------------------------------------------------
__global__ __launch_bounds__(256) void qkv_gemm(
    const float* __restrict__ x, const u16* __restrict__ WT,
    u16* __restrict__ qkv)
{
    const int bm  = blockIdx.x;        // 0..127 (token tiles)
    const int ny  = blockIdx.y;        // 0..47
    const int mat = ny >> 4;           // 0=Q 1=K 2=V
    const int nb  = ny & 15;           // head
    const u16* WTm  = WT  + (size_t)mat * D * D;     // [n][k] bf16
    u16*       outp = qkv + (size_t)mat * M * D;

    __shared__ u16 As[64 * 40];
    __shared__ u16 Bs[64 * 40];

    const int tid  = threadIdx.x;
    const int wave = tid >> 6, ln = tid & 63;
    const int ln15 = ln & 15, quad = ln >> 4;
    const int wm = (wave >> 1) * 32, wn = (wave & 1) * 32;

    const int ar = tid >> 2, ac = (tid & 3) << 3;    // 64 rows x 4 chunks of 8
    const float* aptr = x   + (size_t)(bm * 64 + ar) * D + ac;
    const u16*   bptr = WTm + (size_t)(nb * 64 + ar) * D + ac;

    f32x4 acc[2][2] = {};

    for (int k0 = 0; k0 < D; k0 += 32) {
        bf16x8 av = ld8f(aptr + k0);
        bf16x8 bv = *reinterpret_cast<const bf16x8*>(bptr + k0);
        __syncthreads();
        *reinterpret_cast<bf16x8*>(&As[ar * 40 + ac]) = av;
        *reinterpret_cast<bf16x8*>(&Bs[ar * 40 + ac]) = bv;
        __syncthreads();
        bf16x8 af[2], bfr[2];
        #pragma unroll
        for (int i = 0; i < 2; ++i)
            af[i] = *reinterpret_cast<const bf16x8*>(&As[(wm + i * 16 + ln15) * 40 + quad * 8]);
        #pragma unroll
        for (int j = 0; j < 2; ++j)
            bfr[j] = *reinterpret_cast<const bf16x8*>(&Bs[(wn + j * 16 + ln15) * 40 + quad * 8]);
        #pragma unroll
        for (int i = 0; i < 2; ++i)
            #pragma unroll
            for (int j = 0; j < 2; ++j)
                acc[i][j] = mfma16(af[i], bfr[j], acc[i][j]);
    }

    // epilogue: C/D layout col=lane&15, row=quad*4+reg (m89-verified)
    #pragma unroll
    for (int i = 0; i < 2; ++i)
        #pragma unroll
        for (int j = 0; j < 2; ++j)
            #pragma unroll
            for (int r = 0; r < 4; ++r) {
                int rowl = wm + i * 16 + quad * 4 + r;
                int coll = wn + j * 16 + ln15;            // dh
                int t = bm * 64 + rowl;
                int b = t >> 11, s = t & (S - 1);
                size_t off = (((size_t)(b * H + nb)) * S + s) * Dh + coll;
                outp[off] = f2bf(acc[i][j][r]);
            }
}

// ---------------------------------------------------------------------------
// Flash attention (causal). 1 block = (64 q-rows, one b*h). 4 waves x 16 rows.
// QK^T: K tile is the natural B^T operand. P goes C-layout -> LDS -> A-layout.
// V transposed into LDS (d-major bf16x2 writes).
// ---------------------------------------------------------------------------
__global__ __launch_bounds__(256) void attn_kernel(
    const u16* __restrict__ qkv, u16* __restrict__ attno)
{
    const u16* qb   = qkv;
    const u16* kbuf = qkv + (size_t)M * D;
    const u16* vbuf = qkv + (size_t)2 * M * D;

    const int qblk = blockIdx.x;         // 0..31
    const int bh   = blockIdx.y;         // 0..63
    const int b = bh >> 4, h = bh & 15;

    __shared__ u16 Qs[64 * 72];
    __shared__ u16 Ks[64 * 72];
    __shared__ u16 Vt[64 * 72];          // Vt[d][kpos]
    __shared__ u16 Ps[4][16 * 72];       // per-wave P tile [qrow][kpos]

    const int tid  = threadIdx.x;
    const int wave = tid >> 6, ln = tid & 63;
    const int ln15 = ln & 15, quad = ln >> 4;

    const u16* qp  = qb   + ((size_t)bh * S + qblk * 64) * Dh;
    const u16* kp0 = kbuf + (size_t)bh * S * Dh;
    const u16* vp0 = vbuf + (size_t)bh * S * Dh;

    for (int c = tid; c < 512; c += 256) {
        int r = c >> 3, cc = (c & 7) << 3;
        *reinterpret_cast<bf16x8*>(&Qs[r * 72 + cc]) =
            *reinterpret_cast<const bf16x8*>(&qp[r * 64 + cc]);
    }
    __syncthreads();
    bf16x8 qa[2];
    qa[0] = *reinterpret_cast<const bf16x8*>(&Qs[(wave * 16 + ln15) * 72 + quad * 8]);
    qa[1] = *reinterpret_cast<const bf16x8*>(&Qs[(wave * 16 + ln15) * 72 + 32 + quad * 8]);

    float m_r[4], l_r[4];
    f32x4 oa[4] = {};
    #pragma unroll
    for (int r = 0; r < 4; ++r) { m_r[r] = -1e30f; l_r[r] = 0.f; }

    const int vd = tid & 63, vrg = tid >> 6;

    for (int kblk = 0; kblk <= qblk; ++kblk) {
        const u16* kb = kp0 + (size_t)kblk * 64 * Dh;
        const u16* vb = vp0 + (size_t)kblk * 64 * Dh;
        __syncthreads();                       // prior iter done with Ks/Vt
        for (int c = tid; c < 512; c += 256) {
            int r = c >> 3, cc = (c & 7) << 3;
            *reinterpret_cast<bf16x8*>(&Ks[r * 72 + cc]) =
                *reinterpret_cast<const bf16x8*>(&kb[r * 64 + cc]);
        }
        #pragma unroll
        for (int p = 0; p < 8; ++p) {          // V transpose, coalesced reads
            int kpos = vrg * 16 + p * 2;
            u32 pack = (u32)vb[(size_t)kpos * 64 + vd]
                     | ((u32)vb[(size_t)(kpos + 1) * 64 + vd] << 16);
            *reinterpret_cast<u32*>(&Vt[vd * 72 + kpos]) = pack;
        }
        __syncthreads();

        // S = Q K^T  (Dh=64 -> 2 k-steps)
        f32x4 sf[4] = {};
        #pragma unroll
        for (int j = 0; j < 4; ++j) {
            bf16x8 k0 = *reinterpret_cast<const bf16x8*>(&Ks[(j * 16 + ln15) * 72 + quad * 8]);
            bf16x8 k1 = *reinterpret_cast<const bf16x8*>(&Ks[(j * 16 + ln15) * 72 + 32 + quad * 8]);
            sf[j] = mfma16(qa[0], k0, sf[j]);
            sf[j] = mfma16(qa[1], k1, sf[j]);
        }

        const int qrow0 = qblk * 64 + wave * 16 + quad * 4;
        float rm[4] = {-1e30f, -1e30f, -1e30f, -1e30f};
        #pragma unroll
        for (int j = 0; j < 4; ++j) {
            int kg = kblk * 64 + j * 16 + ln15;
            #pragma unroll
            for (int r = 0; r < 4; ++r) {
                float v = sf[j][r] * 0.125f;       // 1/sqrt(64)
                v = (kg > qrow0 + r) ? -1e30f : v; // causal mask
                sf[j][r] = v;
                rm[r] = fmaxf(rm[r], v);
            }
        }
        #pragma unroll
        for (int r = 0; r < 4; ++r)
            #pragma unroll
            for (int off = 1; off < 16; off <<= 1)
                rm[r] = fmaxf(rm[r], __shfl_xor(rm[r], off, 64));

        float alpha[4], rs[4];
        #pragma unroll
        for (int r = 0; r < 4; ++r) {
            float mn = fmaxf(m_r[r], rm[r]);
            alpha[r] = __expf(m_r[r] - mn);
            m_r[r] = mn;
            rs[r] = 0.f;
        }
        #pragma unroll
        for (int j = 0; j < 4; ++j)
            #pragma unroll
            for (int r = 0; r < 4; ++r) {
                float p = __expf(sf[j][r] - m_r[r]);
                sf[j][r] = p;
                rs[r] += p;
            }
        #pragma unroll
        for (int r = 0; r < 4; ++r) {
            #pragma unroll
            for (int off = 1; off < 16; off <<= 1)
                rs[r] += __shfl_xor(rs[r], off, 64);
            l_r[r] = l_r[r] * alpha[r] + rs[r];
        }
        #pragma unroll
        for (int jd = 0; jd < 4; ++jd)
            #pragma unroll
            for (int r = 0; r < 4; ++r)
                oa[jd][r] *= alpha[r];

        // P: C-layout regs -> LDS -> A-layout frags (per-wave region, no barrier)
        u16* psw = &Ps[wave][0];
        #pragma unroll
        for (int j = 0; j < 4; ++j)
            #pragma unroll
            for (int r = 0; r < 4; ++r)
                psw[(quad * 4 + r) * 72 + j * 16 + ln15] = f2bf(sf[j][r]);

        #pragma unroll
        for (int st = 0; st < 2; ++st) {
            bf16x8 pa = *reinterpret_cast<const bf16x8*>(&psw[ln15 * 72 + st * 32 + quad * 8]);
            #pragma unroll
            for (int jd = 0; jd < 4; ++jd) {
                bf16x8 vv = *reinterpret_cast<const bf16x8*>(&Vt[(jd * 16 + ln15) * 72 + st * 32 + quad * 8]);
                oa[jd] = mfma16(pa, vv, oa[jd]);
            }
        }
    }

    // epilogue: write token-major [b*S+s][h*64+d] for the output projection
    #pragma unroll
    for (int jd = 0; jd < 4; ++jd)
        #pragma unroll
        for (int r = 0; r < 4; ++r) {
            int qrow = qblk * 64 + wave * 16 + quad * 4 + r;
            size_t off = ((size_t)(b * S + qrow)) * D + h * Dh + jd * 16 + ln15;
            attno[off] = f2bf(oa[jd][r] / l_r[r]);
        }
}

// ---------------------------------------------------------------------------
// Output projection + fp32 bias: bf16 [8192x1024] @ bf16 WoT -> FP32 d_out
// ---------------------------------------------------------------------------
__global__ __launch_bounds__(256) void proj_gemm(
    const u16* __restrict__ A, const u16* __restrict__ WoT,
    const float* __restrict__ bo, float* __restrict__ out)
{
    const int bm = blockIdx.x;     // 0..127
    const int nb = blockIdx.y;     // 0..15
    const int n0 = nb * 64;

    __shared__ u16 As[64 * 40];
    __shared__ u16 Bs[64 * 40];

    const int tid  = threadIdx.x;
    const int wave = tid >> 6, ln = tid & 63;
    const int ln15 = ln & 15, quad = ln >> 4;
    const int wm = (wave >> 1) * 32, wn = (wave & 1) * 32;

    const int ar = tid >> 2, ac = (tid & 3) << 3;
    const u16* aptr = A   + (size_t)(bm * 64 + ar) * D + ac;
    const u16* bptr = WoT + (size_t)(n0 + ar) * D + ac;

    f32x4 acc[2][2] = {};

    for (int k0 = 0; k0 < D; k0 += 32) {
        bf16x8 av = *reinterpret_cast<const bf16x8*>(aptr + k0);
        bf16x8 bv = *reinterpret_cast<const bf16x8*>(bptr + k0);
        __syncthreads();
        *reinterpret_cast<bf16x8*>(&As[ar * 40 + ac]) = av;
        *reinterpret_cast<bf16x8*>(&Bs[ar * 40 + ac]) = bv;
        __syncthreads();
        bf16x8 af[2], bfr[2];
        #pragma unroll
        for (int i = 0; i < 2; ++i)
            af[i] = *reinterpret_cast<const bf16x8*>(&As[(wm + i * 16 + ln15) * 40 + quad * 8]);
        #pragma unroll
        for (int j = 0; j < 2; ++j)
            bfr[j] = *reinterpret_cast<const bf16x8*>(&Bs[(wn + j * 16 + ln15) * 40 + quad * 8]);
        #pragma unroll
        for (int i = 0; i < 2; ++i)
            #pragma unroll
            for (int j = 0; j < 2; ++j)
                acc[i][j] = mfma16(af[i], bfr[j], acc[i][j]);
    }

    #pragma unroll
    for (int i = 0; i < 2; ++i)
        #pragma unroll
        for (int j = 0; j < 2; ++j)
            #pragma unroll
            for (int r = 0; r < 4; ++r) {
                int rowl = wm + i * 16 + quad * 4 + r;
                int col  = n0 + wn + j * 16 + ln15;
                float v = acc[i][j][r] + bo[col];
                out[(size_t)(bm * 64 + rowl) * D + col] = v;   // fp32 output
            }
}

extern "C" void kernel_launch(void* const* d_in, const int* in_sizes, int n_in,
                              void* d_out, int out_size, void* d_ws, size_t ws_size,
                              hipStream_t stream) {
    const float* x  = (const float*)d_in[0];
    const float* Wq = (const float*)d_in[1];
    const float* Wk = (const float*)d_in[2];
    const float* Wv = (const float*)d_in[3];
    const float* Wo = (const float*)d_in[4];
    const float* bo = (const float*)d_in[5];
    float* out = (float*)d_out;
    u16* ws  = (u16*)d_ws;

    u16* WT   = ws;                                   // 4 * 1M bf16 (8 MB)
    u16* qkv  = ws + (size_t)4 * D * D;               // 3 * 8M bf16 (48 MB)
    u16* attn = qkv + (size_t)3 * M * D;              // 8M bf16 (16 MB)

    transpose_w<<<dim3(16, 16, 4), 256, 0, stream>>>(Wq, Wk, Wv, Wo, WT);
    qkv_gemm  <<<dim3(128, 48),    256, 0, stream>>>(x, WT, qkv);
    attn_kernel<<<dim3(32, 64),    256, 0, stream>>>(qkv, attn);
    proj_gemm <<<dim3(128, 16),    256, 0, stream>>>(attn, WT + (size_t)3 * D * D, bo, out);
}

// Round 4
// 385.521 us; speedup vs baseline: 1.2791x; 1.2791x over previous
//
#include <hip/hip_runtime.h>
#include <hip/hip_bf16.h>

#define DEV __device__ __forceinline__

typedef unsigned short u16;
typedef unsigned int u32;
typedef __bf16 bf16x8 __attribute__((ext_vector_type(8)));
typedef float f32x4 __attribute__((ext_vector_type(4)));

static constexpr int S   = 2048;
static constexpr int D   = 1024;
static constexpr int H   = 16;
static constexpr int Dh  = 64;
static constexpr int B_  = 4;
static constexpr int M   = B_ * S;   // 8192 tokens

DEV u16 f2bf(float f) {
    __hip_bfloat16 h = __float2bfloat16(f);
    union { __hip_bfloat16 h; u16 u; } cv; cv.h = h; return cv.u;
}
DEV float bf2f(u16 u) {
    union { u16 u; __hip_bfloat16 h; } cv; cv.u = u; return __bfloat162float(cv.h);
}
DEV f32x4 mfma16(bf16x8 a, bf16x8 b, f32x4 c) {
    return __builtin_amdgcn_mfma_f32_16x16x32_bf16(a, b, c, 0, 0, 0);
}
// load 8 contiguous fp32, round to 8 bf16 (two float4 vector loads)
DEV bf16x8 ld8f(const float* p) {
    const f32x4* q = reinterpret_cast<const f32x4*>(p);
    f32x4 a = q[0], b = q[1];
    union { u16 u[8]; bf16x8 v; } r;
    r.u[0] = f2bf(a[0]); r.u[1] = f2bf(a[1]); r.u[2] = f2bf(a[2]); r.u[3] = f2bf(a[3]);
    r.u[4] = f2bf(b[0]); r.u[5] = f2bf(b[1]); r.u[6] = f2bf(b[2]); r.u[7] = f2bf(b[3]);
    return r.v;
}

// ---------------------------------------------------------------------------
// Transpose + bf16-convert the 4 fp32 weight matrices [K][N] -> bf16 [N][K]
// ---------------------------------------------------------------------------
__global__ __launch_bounds__(256) void transpose_w(
    const float* __restrict__ Wq, const float* __restrict__ Wk,
    const float* __restrict__ Wv, const float* __restrict__ Wo,
    u16* __restrict__ WT)
{
    const float* src = blockIdx.z == 0 ? Wq : blockIdx.z == 1 ? Wk
                     : blockIdx.z == 2 ? Wv : Wo;
    u16* dst = WT + (size_t)blockIdx.z * D * D;
    __shared__ u16 T[64 * 72];
    const int k0 = blockIdx.x * 64, n0 = blockIdx.y * 64;
    const int tid = threadIdx.x;
    for (int c = tid; c < 512; c += 256) {
        int r = c >> 3, cc = (c & 7) << 3;
        *reinterpret_cast<bf16x8*>(&T[r * 72 + cc]) =
            ld8f(&src[(size_t)(k0 + r) * D + n0 + cc]);
    }
    __syncthreads();
    for (int c = tid; c < 512; c += 256) {
        int r = c >> 3, cc = (c & 7) << 3;   // r: n-row of dst tile, cc: k-chunk
        u16 tmp[8];
        #pragma unroll
        for (int i = 0; i < 8; ++i) tmp[i] = T[(cc + i) * 72 + r];
        *reinterpret_cast<bf16x8*>(&dst[(size_t)(n0 + r) * D + k0 + cc]) =
            *reinterpret_cast<const bf16x8*>(tmp);
    }
}

// ---------------------------------------------------------------------------
// Fused QKV GEMM: block = 64 tokens x 1 head, computes Q,K,V (3 mats) off one
// A-stage per k-step: 12 MFMA per stage instead of 4. BK=32, LDS stride 32.
// ---------------------------------------------------------------------------
__global__ __launch_bounds__(256) void qkv_gemm(
    const float* __restrict__ x, const u16* __restrict__ WT,
    u16* __restrict__ qkv)
{
    const int bm = blockIdx.x;         // 0..127 (token tiles)
    const int nb = blockIdx.y;         // 0..15 (head)

    __shared__ u16 As[64 * 32];
    __shared__ u16 Bs[3][64 * 32];

    const int tid  = threadIdx.x;
    const int wave = tid >> 6, ln = tid & 63;
    const int ln15 = ln & 15, quad = ln >> 4;
    const int wm = (wave >> 1) * 32, wn = (wave & 1) * 32;

    const int ar = tid >> 2, ac = (tid & 3) << 3;    // 64 rows x 4 chunks of 8
    const float* aptr = x  + (size_t)(bm * 64 + ar) * D + ac;
    const u16*   bptr = WT + (size_t)(nb * 64 + ar) * D + ac;

    f32x4 acc[3][2][2] = {};

    for (int k0 = 0; k0 < D; k0 += 32) {
        bf16x8 av  = ld8f(aptr + k0);
        bf16x8 bv0 = *reinterpret_cast<const bf16x8*>(bptr + k0);
        bf16x8 bv1 = *reinterpret_cast<const bf16x8*>(bptr + (size_t)D * D + k0);
        bf16x8 bv2 = *reinterpret_cast<const bf16x8*>(bptr + (size_t)2 * D * D + k0);
        __syncthreads();
        *reinterpret_cast<bf16x8*>(&As[ar * 32 + ac])    = av;
        *reinterpret_cast<bf16x8*>(&Bs[0][ar * 32 + ac]) = bv0;
        *reinterpret_cast<bf16x8*>(&Bs[1][ar * 32 + ac]) = bv1;
        *reinterpret_cast<bf16x8*>(&Bs[2][ar * 32 + ac]) = bv2;
        __syncthreads();
        bf16x8 af[2];
        #pragma unroll
        for (int i = 0; i < 2; ++i)
            af[i] = *reinterpret_cast<const bf16x8*>(&As[(wm + i * 16 + ln15) * 32 + quad * 8]);
        #pragma unroll
        for (int mat = 0; mat < 3; ++mat) {
            #pragma unroll
            for (int j = 0; j < 2; ++j) {
                bf16x8 bfr = *reinterpret_cast<const bf16x8*>(&Bs[mat][(wn + j * 16 + ln15) * 32 + quad * 8]);
                #pragma unroll
                for (int i = 0; i < 2; ++i)
                    acc[mat][i][j] = mfma16(af[i], bfr, acc[mat][i][j]);
            }
        }
    }

    // epilogue: C/D layout col=lane&15, row=quad*4+reg (m89-verified)
    #pragma unroll
    for (int mat = 0; mat < 3; ++mat) {
        u16* outp = qkv + (size_t)mat * M * D;
        #pragma unroll
        for (int i = 0; i < 2; ++i)
            #pragma unroll
            for (int j = 0; j < 2; ++j)
                #pragma unroll
                for (int r = 0; r < 4; ++r) {
                    int rowl = wm + i * 16 + quad * 4 + r;
                    int coll = wn + j * 16 + ln15;            // dh
                    int t = bm * 64 + rowl;
                    int b = t >> 11, s = t & (S - 1);
                    size_t off = (((size_t)(b * H + nb)) * S + s) * Dh + coll;
                    outp[off] = f2bf(acc[mat][i][j][r]);
                }
    }
}

// ---------------------------------------------------------------------------
// V [bh][s][dh] -> Vt [bh][dh][s]  (one-shot, coalesced via LDS tile)
// ---------------------------------------------------------------------------
__global__ __launch_bounds__(256) void vt_transpose(
    const u16* __restrict__ v, u16* __restrict__ vtout)
{
    const int st = blockIdx.x;   // s-tile 0..31
    const int bh = blockIdx.y;   // 0..63
    __shared__ u16 T[64 * 72];
    const u16* src = v + ((size_t)bh * S + st * 64) * Dh;
    u16* dst = vtout + (size_t)bh * Dh * S + st * 64;
    const int tid = threadIdx.x;
    for (int c = tid; c < 512; c += 256) {
        int r = c >> 3, cc = (c & 7) << 3;     // r = s row, cc = dh chunk
        *reinterpret_cast<bf16x8*>(&T[r * 72 + cc]) =
            *reinterpret_cast<const bf16x8*>(&src[r * 64 + cc]);
    }
    __syncthreads();
    for (int c = tid; c < 512; c += 256) {
        int r = c >> 3, cc = (c & 7) << 3;     // r = dh row, cc = s chunk
        u16 tmp[8];
        #pragma unroll
        for (int i = 0; i < 8; ++i) tmp[i] = T[(cc + i) * 72 + r];
        *reinterpret_cast<bf16x8*>(&dst[(size_t)r * S + cc]) =
            *reinterpret_cast<const bf16x8*>(tmp);
    }
}

// ---------------------------------------------------------------------------
// Flash attention (causal), paired q-tiles for load balance.
// Block = (q-tiles lo=bx and hi=31-bx, one b*h). Every block: 33 tile-iters.
// K staged [kpos][dh]; V staged from pre-transposed Vt as [dh][kpos].
// Mask applied only on the diagonal k-block. Q pre-scaled by 1/8 in regs.
// ---------------------------------------------------------------------------
__global__ __launch_bounds__(256) void attn_kernel(
    const u16* __restrict__ qbuf, const u16* __restrict__ kbuf,
    const u16* __restrict__ vt, u16* __restrict__ attno)
{
    const int lo = blockIdx.x;          // 0..15
    const int hi = 31 - lo;             // 16..31
    const int bh = blockIdx.y;          // 0..63
    const int b = bh >> 4, h = bh & 15;

    __shared__ u16 Ks[64 * 72];
    __shared__ u16 Vs[64 * 72];         // [dh][kpos]
    __shared__ u16 Ps[4][16 * 72];      // per-wave P tile

    const int tid  = threadIdx.x;
    const int wave = tid >> 6, ln = tid & 63;
    const int ln15 = ln & 15, quad = ln >> 4;

    const u16* kp0 = kbuf + (size_t)bh * S * Dh;
    const u16* vp0 = vt   + (size_t)bh * Dh * S;

    // Q fragments for both tiles, pre-scaled by 1/sqrt(Dh), staged via Ks
    bf16x8 qf[2][2];
    #pragma unroll
    for (int t = 0; t < 2; ++t) {
        const int qt = t ? hi : lo;
        const u16* qp = qbuf + ((size_t)bh * S + qt * 64) * Dh;
        for (int c = tid; c < 512; c += 256) {
            int r = c >> 3, cc = (c & 7) << 3;
            *reinterpret_cast<bf16x8*>(&Ks[r * 72 + cc]) =
                *reinterpret_cast<const bf16x8*>(&qp[r * 64 + cc]);
        }
        __syncthreads();
        #pragma unroll
        for (int st = 0; st < 2; ++st) {
            union { bf16x8 v; u16 u[8]; } in, ot;
            in.v = *reinterpret_cast<const bf16x8*>(&Ks[(wave * 16 + ln15) * 72 + st * 32 + quad * 8]);
            #pragma unroll
            for (int i = 0; i < 8; ++i) ot.u[i] = f2bf(bf2f(in.u[i]) * 0.125f);
            qf[t][st] = ot.v;
        }
        __syncthreads();
    }

    float m_st[2][4], l_st[2][4];
    f32x4 o_st[2][4] = {};
    #pragma unroll
    for (int t = 0; t < 2; ++t)
        #pragma unroll
        for (int r = 0; r < 4; ++r) { m_st[t][r] = -3e38f; l_st[t][r] = 0.f; }

    u16* psw = &Ps[wave][0];
    const int lrow = wave * 16 + quad * 4;

    auto step = [&](const bf16x8* qa, float* m_r, float* l_r, f32x4* oa, bool domask) {
        f32x4 sf[4] = {};
        #pragma unroll
        for (int j = 0; j < 4; ++j) {
            bf16x8 k0 = *reinterpret_cast<const bf16x8*>(&Ks[(j * 16 + ln15) * 72 + quad * 8]);
            bf16x8 k1 = *reinterpret_cast<const bf16x8*>(&Ks[(j * 16 + ln15) * 72 + 32 + quad * 8]);
            sf[j] = mfma16(qa[0], k0, sf[j]);
            sf[j] = mfma16(qa[1], k1, sf[j]);
        }
        float rm[4] = {-3e38f, -3e38f, -3e38f, -3e38f};
        if (domask) {
            #pragma unroll
            for (int j = 0; j < 4; ++j) {
                int kg = j * 16 + ln15;
                #pragma unroll
                for (int r = 0; r < 4; ++r) {
                    float v = (kg > lrow + r) ? -3e38f : sf[j][r];
                    sf[j][r] = v;
                    rm[r] = fmaxf(rm[r], v);
                }
            }
        } else {
            #pragma unroll
            for (int j = 0; j < 4; ++j)
                #pragma unroll
                for (int r = 0; r < 4; ++r)
                    rm[r] = fmaxf(rm[r], sf[j][r]);
        }
        #pragma unroll
        for (int r = 0; r < 4; ++r)
            #pragma unroll
            for (int off = 1; off < 16; off <<= 1)
                rm[r] = fmaxf(rm[r], __shfl_xor(rm[r], off, 64));

        float alpha[4], rs[4];
        #pragma unroll
        for (int r = 0; r < 4; ++r) {
            float mn = fmaxf(m_r[r], rm[r]);
            alpha[r] = __expf(m_r[r] - mn);
            m_r[r] = mn;
            rs[r] = 0.f;
        }
        #pragma unroll
        for (int j = 0; j < 4; ++j)
            #pragma unroll
            for (int r = 0; r < 4; ++r) {
                float p = __expf(sf[j][r] - m_r[r]);
                sf[j][r] = p;
                rs[r] += p;
            }
        #pragma unroll
        for (int r = 0; r < 4; ++r) {
            #pragma unroll
            for (int off = 1; off < 16; off <<= 1)
                rs[r] += __shfl_xor(rs[r], off, 64);
            l_r[r] = l_r[r] * alpha[r] + rs[r];
        }
        #pragma unroll
        for (int jd = 0; jd < 4; ++jd)
            #pragma unroll
            for (int r = 0; r < 4; ++r)
                oa[jd][r] *= alpha[r];

        // P: C-layout regs -> per-wave LDS -> A-layout frags (in-wave ordering)
        #pragma unroll
        for (int j = 0; j < 4; ++j)
            #pragma unroll
            for (int r = 0; r < 4; ++r)
                psw[(quad * 4 + r) * 72 + j * 16 + ln15] = f2bf(sf[j][r]);

        #pragma unroll
        for (int st = 0; st < 2; ++st) {
            bf16x8 pa = *reinterpret_cast<const bf16x8*>(&psw[ln15 * 72 + st * 32 + quad * 8]);
            #pragma unroll
            for (int jd = 0; jd < 4; ++jd) {
                bf16x8 vv = *reinterpret_cast<const bf16x8*>(&Vs[(jd * 16 + ln15) * 72 + st * 32 + quad * 8]);
                oa[jd] = mfma16(pa, vv, oa[jd]);
            }
        }
    };

    for (int kblk = 0; kblk <= hi; ++kblk) {
        __syncthreads();                     // prior iter done with Ks/Vs
        for (int c = tid; c < 512; c += 256) {
            int r = c >> 3, cc = (c & 7) << 3;
            *reinterpret_cast<bf16x8*>(&Ks[r * 72 + cc]) =
                *reinterpret_cast<const bf16x8*>(&kp0[((size_t)kblk * 64 + r) * Dh + cc]);
            *reinterpret_cast<bf16x8*>(&Vs[r * 72 + cc]) =
                *reinterpret_cast<const bf16x8*>(&vp0[(size_t)r * S + kblk * 64 + cc]);
        }
        __syncthreads();
        step(qf[1], m_st[1], l_st[1], o_st[1], kblk == hi);
        if (kblk <= lo)
            step(qf[0], m_st[0], l_st[0], o_st[0], kblk == lo);
    }

    // epilogue: token-major [b*S+s][h*64+d]
    #pragma unroll
    for (int t = 0; t < 2; ++t) {
        const int qt = t ? hi : lo;
        #pragma unroll
        for (int jd = 0; jd < 4; ++jd)
            #pragma unroll
            for (int r = 0; r < 4; ++r) {
                int qrow = qt * 64 + wave * 16 + quad * 4 + r;
                size_t off = ((size_t)(b * S + qrow)) * D + h * Dh + jd * 16 + ln15;
                attno[off] = f2bf(o_st[t][jd][r] / l_st[t][r]);
            }
    }
}

// ---------------------------------------------------------------------------
// Output projection + fp32 bias: bf16 [8192x1024] @ bf16 WoT -> FP32 d_out
// ---------------------------------------------------------------------------
__global__ __launch_bounds__(256) void proj_gemm(
    const u16* __restrict__ A, const u16* __restrict__ WoT,
    const float* __restrict__ bo, float* __restrict__ out)
{
    const int bm = blockIdx.x;     // 0..127
    const int nb = blockIdx.y;     // 0..15
    const int n0 = nb * 64;

    __shared__ u16 As[64 * 40];
    __shared__ u16 Bs[64 * 40];

    const int tid  = threadIdx.x;
    const int wave = tid >> 6, ln = tid & 63;
    const int ln15 = ln & 15, quad = ln >> 4;
    const int wm = (wave >> 1) * 32, wn = (wave & 1) * 32;

    const int ar = tid >> 2, ac = (tid & 3) << 3;
    const u16* aptr = A   + (size_t)(bm * 64 + ar) * D + ac;
    const u16* bptr = WoT + (size_t)(n0 + ar) * D + ac;

    f32x4 acc[2][2] = {};

    for (int k0 = 0; k0 < D; k0 += 32) {
        bf16x8 av = *reinterpret_cast<const bf16x8*>(aptr + k0);
        bf16x8 bv = *reinterpret_cast<const bf16x8*>(bptr + k0);
        __syncthreads();
        *reinterpret_cast<bf16x8*>(&As[ar * 40 + ac]) = av;
        *reinterpret_cast<bf16x8*>(&Bs[ar * 40 + ac]) = bv;
        __syncthreads();
        bf16x8 af[2], bfr[2];
        #pragma unroll
        for (int i = 0; i < 2; ++i)
            af[i] = *reinterpret_cast<const bf16x8*>(&As[(wm + i * 16 + ln15) * 40 + quad * 8]);
        #pragma unroll
        for (int j = 0; j < 2; ++j)
            bfr[j] = *reinterpret_cast<const bf16x8*>(&Bs[(wn + j * 16 + ln15) * 40 + quad * 8]);
        #pragma unroll
        for (int i = 0; i < 2; ++i)
            #pragma unroll
            for (int j = 0; j < 2; ++j)
                acc[i][j] = mfma16(af[i], bfr[j], acc[i][j]);
    }

    #pragma unroll
    for (int i = 0; i < 2; ++i)
        #pragma unroll
        for (int j = 0; j < 2; ++j)
            #pragma unroll
            for (int r = 0; r < 4; ++r) {
                int rowl = wm + i * 16 + quad * 4 + r;
                int col  = n0 + wn + j * 16 + ln15;
                float v = acc[i][j][r] + bo[col];
                out[(size_t)(bm * 64 + rowl) * D + col] = v;   // fp32 output
            }
}

extern "C" void kernel_launch(void* const* d_in, const int* in_sizes, int n_in,
                              void* d_out, int out_size, void* d_ws, size_t ws_size,
                              hipStream_t stream) {
    const float* x  = (const float*)d_in[0];
    const float* Wq = (const float*)d_in[1];
    const float* Wk = (const float*)d_in[2];
    const float* Wv = (const float*)d_in[3];
    const float* Wo = (const float*)d_in[4];
    const float* bo = (const float*)d_in[5];
    float* out = (float*)d_out;
    u16* ws  = (u16*)d_ws;

    u16* WT   = ws;                                   // 4 * 1M bf16 (8 MB)
    u16* qkvb = ws + (size_t)4 * D * D;               // 3 * 8M bf16 (48 MB)
    u16* vtb  = qkvb + (size_t)3 * M * D;             // 8M bf16 (16 MB) -> 72 MB total
    u16* kb   = qkvb + (size_t)M * D;
    u16* vb   = qkvb + (size_t)2 * M * D;
    u16* attn = vb;                                   // reuse V slot (dead after vt_transpose)

    transpose_w<<<dim3(16, 16, 4), 256, 0, stream>>>(Wq, Wk, Wv, Wo, WT);
    qkv_gemm   <<<dim3(128, 16),   256, 0, stream>>>(x, WT, qkvb);
    vt_transpose<<<dim3(32, 64),   256, 0, stream>>>(vb, vtb);
    attn_kernel<<<dim3(16, 64),    256, 0, stream>>>(qkvb, kb, vtb, attn);
    proj_gemm  <<<dim3(128, 16),   256, 0, stream>>>(attn, WT + (size_t)3 * D * D, bo, out);
}

// Round 6
// 304.414 us; speedup vs baseline: 1.6199x; 1.2664x over previous
//
#include <hip/hip_runtime.h>
#include <hip/hip_bf16.h>

#define DEV __device__ __forceinline__

typedef unsigned short u16;
typedef unsigned int u32;
typedef __bf16 bf16x8 __attribute__((ext_vector_type(8)));
typedef float f32x4 __attribute__((ext_vector_type(4)));

static constexpr int S   = 2048;
static constexpr int D   = 1024;
static constexpr int H   = 16;
static constexpr int Dh  = 64;
static constexpr int B_  = 4;
static constexpr int M   = B_ * S;   // 8192 tokens

DEV u16 f2bf(float f) {
    __hip_bfloat16 h = __float2bfloat16(f);
    union { __hip_bfloat16 h; u16 u; } cv; cv.h = h; return cv.u;
}
DEV float bf2f(u16 u) {
    union { u16 u; __hip_bfloat16 h; } cv; cv.u = u; return __bfloat162float(cv.h);
}
DEV f32x4 mfma16(bf16x8 a, bf16x8 b, f32x4 c) {
    return __builtin_amdgcn_mfma_f32_16x16x32_bf16(a, b, c, 0, 0, 0);
}
// async global->LDS, 16B per lane; lds dest = wave-uniform base + lane*16
DEV void llds16(const u16* g, u16* l) {
    __builtin_amdgcn_global_load_lds(
        (const __attribute__((address_space(1))) u32*)g,
        (__attribute__((address_space(3))) u32*)l, 16, 0, 0);
}
// load 8 contiguous fp32, round to 8 bf16
DEV bf16x8 ld8f(const float* p) {
    const f32x4* q = reinterpret_cast<const f32x4*>(p);
    f32x4 a = q[0], b = q[1];
    union { u16 u[8]; bf16x8 v; } r;
    r.u[0] = f2bf(a[0]); r.u[1] = f2bf(a[1]); r.u[2] = f2bf(a[2]); r.u[3] = f2bf(a[3]);
    r.u[4] = f2bf(b[0]); r.u[5] = f2bf(b[1]); r.u[6] = f2bf(b[2]); r.u[7] = f2bf(b[3]);
    return r.v;
}

// ---------------------------------------------------------------------------
// x fp32 -> bf16 (one-shot)
// ---------------------------------------------------------------------------
__global__ __launch_bounds__(256) void x_to_bf16(
    const float* __restrict__ x, u16* __restrict__ xb)
{
    size_t i = ((size_t)blockIdx.x * 256 + threadIdx.x) * 8;
    *reinterpret_cast<bf16x8*>(xb + i) = ld8f(x + i);
}

// ---------------------------------------------------------------------------
// Transpose + bf16-convert the 4 fp32 weight matrices [K][N] -> bf16 [N][K]
// ---------------------------------------------------------------------------
__global__ __launch_bounds__(256) void transpose_w(
    const float* __restrict__ Wq, const float* __restrict__ Wk,
    const float* __restrict__ Wv, const float* __restrict__ Wo,
    u16* __restrict__ WT)
{
    const float* src = blockIdx.z == 0 ? Wq : blockIdx.z == 1 ? Wk
                     : blockIdx.z == 2 ? Wv : Wo;
    u16* dst = WT + (size_t)blockIdx.z * D * D;
    __shared__ u16 T[64 * 72];
    const int k0 = blockIdx.x * 64, n0 = blockIdx.y * 64;
    const int tid = threadIdx.x;
    for (int c = tid; c < 512; c += 256) {
        int r = c >> 3, cc = (c & 7) << 3;
        *reinterpret_cast<bf16x8*>(&T[r * 72 + cc]) =
            ld8f(&src[(size_t)(k0 + r) * D + n0 + cc]);
    }
    __syncthreads();
    for (int c = tid; c < 512; c += 256) {
        int r = c >> 3, cc = (c & 7) << 3;
        u16 tmp[8];
        #pragma unroll
        for (int i = 0; i < 8; ++i) tmp[i] = T[(cc + i) * 72 + r];
        *reinterpret_cast<bf16x8*>(&dst[(size_t)(n0 + r) * D + k0 + cc]) =
            *reinterpret_cast<const bf16x8*>(tmp);
    }
}

// ---------------------------------------------------------------------------
// 128x128 m97-style GEMM: A bf16 [M][1024] x WT bf16 [3072][1024] -> qkv
// (Q,K,V stacked in N). BK=32, global_load_lds(16B) staging, 2-barrier K-loop.
// Epilogue scatters to [mat][b*H+h][s][dh].
// ---------------------------------------------------------------------------
__global__ __launch_bounds__(256) void qkv_gemm128(
    const u16* __restrict__ A, const u16* __restrict__ WT,
    u16* __restrict__ qkv)
{
    const int bm = blockIdx.x;     // 0..63
    const int bn = blockIdx.y;     // 0..23

    __shared__ u16 As[128 * 32];
    __shared__ u16 Bs[128 * 32];

    const int tid  = threadIdx.x;
    const int wave = tid >> 6, ln = tid & 63;
    const int ln15 = ln & 15, quad = ln >> 4;
    const int wm = (wave >> 1) * 64, wn = (wave & 1) * 64;

    const u16* Ab = A  + (size_t)(bm * 128) * D;
    const u16* Bb = WT + (size_t)(bn * 128) * D;

    // per-lane chunk coords for the two staging calls of this wave
    const int c0  = wave * 128 + ln;         // call 0 chunk
    const int c1  = c0 + 64;                 // call 1 chunk
    const int r0  = c0 >> 2, o0 = (c0 & 3) * 8;
    const int r1  = c1 >> 2, o1 = (c1 & 3) * 8;

    f32x4 acc[4][4] = {};

    for (int k0 = 0; k0 < D; k0 += 32) {
        __syncthreads();
        llds16(Ab + (size_t)r0 * D + k0 + o0, &As[(wave * 2 + 0) * 512]);
        llds16(Ab + (size_t)r1 * D + k0 + o1, &As[(wave * 2 + 1) * 512]);
        llds16(Bb + (size_t)r0 * D + k0 + o0, &Bs[(wave * 2 + 0) * 512]);
        llds16(Bb + (size_t)r1 * D + k0 + o1, &Bs[(wave * 2 + 1) * 512]);
        __syncthreads();
        bf16x8 af[4], bfr[4];
        #pragma unroll
        for (int i = 0; i < 4; ++i)
            af[i] = *reinterpret_cast<const bf16x8*>(&As[(wm + i * 16 + ln15) * 32 + quad * 8]);
        #pragma unroll
        for (int j = 0; j < 4; ++j)
            bfr[j] = *reinterpret_cast<const bf16x8*>(&Bs[(wn + j * 16 + ln15) * 32 + quad * 8]);
        #pragma unroll
        for (int i = 0; i < 4; ++i)
            #pragma unroll
            for (int j = 0; j < 4; ++j)
                acc[i][j] = mfma16(af[i], bfr[j], acc[i][j]);
    }

    const int matn = bn >> 3;                       // 0=Q 1=K 2=V (wave-uniform)
    u16* outp = qkv + (size_t)matn * M * D;
    #pragma unroll
    for (int i = 0; i < 4; ++i)
        #pragma unroll
        for (int j = 0; j < 4; ++j)
            #pragma unroll
            for (int r = 0; r < 4; ++r) {
                int t = bm * 128 + wm + i * 16 + quad * 4 + r;
                int b = t >> 11, s = t & (S - 1);
                int n = (bn & 7) * 128 + wn + j * 16 + ln15;   // 0..1023 in-mat
                int head = n >> 6, dh = n & 63;
                outp[(((size_t)(b * H + head)) * S + s) * Dh + dh] = f2bf(acc[i][j][r]);
            }
}

// ---------------------------------------------------------------------------
// V [bh][s][dh] -> Vt [bh][dh][s]  (one-shot, coalesced via LDS tile)
// ---------------------------------------------------------------------------
__global__ __launch_bounds__(256) void vt_transpose(
    const u16* __restrict__ v, u16* __restrict__ vtout)
{
    const int st = blockIdx.x;   // s-tile 0..31
    const int bh = blockIdx.y;   // 0..63
    __shared__ u16 T[64 * 72];
    const u16* src = v + ((size_t)bh * S + st * 64) * Dh;
    u16* dst = vtout + (size_t)bh * Dh * S + st * 64;
    const int tid = threadIdx.x;
    for (int c = tid; c < 512; c += 256) {
        int r = c >> 3, cc = (c & 7) << 3;
        *reinterpret_cast<bf16x8*>(&T[r * 72 + cc]) =
            *reinterpret_cast<const bf16x8*>(&src[r * 64 + cc]);
    }
    __syncthreads();
    for (int c = tid; c < 512; c += 256) {
        int r = c >> 3, cc = (c & 7) << 3;
        u16 tmp[8];
        #pragma unroll
        for (int i = 0; i < 8; ++i) tmp[i] = T[(cc + i) * 72 + r];
        *reinterpret_cast<bf16x8*>(&dst[(size_t)r * S + cc]) =
            *reinterpret_cast<const bf16x8*>(tmp);
    }
}

// ---------------------------------------------------------------------------
// Flash attention (causal), paired q-tiles, FIXED-OFFSET softmax:
// q pre-scaled by 0.125*log2(e); p = 2^(s - 24); unnormalized O accumulate;
// per-lane l partials; single shuffle-reduce + divide at the epilogue.
// K/V staged via global_load_lds (unpadded), V from pre-transposed Vt.
// P-tile stride 72 (row len 64 + 8 pad; stride >= 64 REQUIRED — stride 40
// in round 5 overlapped rows and corrupted P).
// ---------------------------------------------------------------------------
__global__ __launch_bounds__(256) void attn_kernel(
    const u16* __restrict__ qbuf, const u16* __restrict__ kbuf,
    const u16* __restrict__ vt, u16* __restrict__ attno)
{
    const int lo = blockIdx.x;          // 0..15
    const int hi = 31 - lo;             // 16..31
    const int bh = blockIdx.y;          // 0..63
    const int b = bh >> 4, h = bh & 15;

    __shared__ u16 Ks[64 * 64];
    __shared__ u16 Vs[64 * 64];         // [dh][kpos]
    __shared__ u16 Ps[4][16 * 72];      // per-wave P tile, stride 72

    const int tid  = threadIdx.x;
    const int wave = tid >> 6, ln = tid & 63;
    const int ln15 = ln & 15, quad = ln >> 4;

    const u16* kp0 = kbuf + (size_t)bh * S * Dh;
    const u16* vp0 = vt   + (size_t)bh * Dh * S;

    // Q fragments for both tiles, pre-scaled by 0.125*log2e, staged via Ks
    bf16x8 qf[2][2];
    #pragma unroll
    for (int t = 0; t < 2; ++t) {
        const int qt = t ? hi : lo;
        const u16* qp = qbuf + ((size_t)bh * S + qt * 64) * Dh;
        for (int c = tid; c < 512; c += 256) {
            int r = c >> 3, cc = (c & 7) << 3;
            *reinterpret_cast<bf16x8*>(&Ks[r * 64 + cc]) =
                *reinterpret_cast<const bf16x8*>(&qp[r * 64 + cc]);
        }
        __syncthreads();
        #pragma unroll
        for (int st = 0; st < 2; ++st) {
            union { bf16x8 v; u16 u[8]; } in, ot;
            in.v = *reinterpret_cast<const bf16x8*>(&Ks[(wave * 16 + ln15) * 64 + st * 32 + quad * 8]);
            #pragma unroll
            for (int i = 0; i < 8; ++i) ot.u[i] = f2bf(bf2f(in.u[i]) * 0.18033688f);
            qf[t][st] = ot.v;
        }
        __syncthreads();
    }

    float l_st[2][4] = {};
    f32x4 o_st[2][4] = {};

    u16* psw = &Ps[wave][0];
    const int lrow = wave * 16 + quad * 4;

    auto step = [&](const bf16x8* qa, float* l_r, f32x4* oa, bool domask) {
        f32x4 sf[4] = {};
        #pragma unroll
        for (int j = 0; j < 4; ++j) {
            bf16x8 k0 = *reinterpret_cast<const bf16x8*>(&Ks[(j * 16 + ln15) * 64 + quad * 8]);
            bf16x8 k1 = *reinterpret_cast<const bf16x8*>(&Ks[(j * 16 + ln15) * 64 + 32 + quad * 8]);
            sf[j] = mfma16(qa[0], k0, sf[j]);
            sf[j] = mfma16(qa[1], k1, sf[j]);
        }
        if (domask) {
            #pragma unroll
            for (int j = 0; j < 4; ++j) {
                int kg = j * 16 + ln15;
                #pragma unroll
                for (int r = 0; r < 4; ++r)
                    if (kg > lrow + r) sf[j][r] = -3e38f;
            }
        }
        #pragma unroll
        for (int j = 0; j < 4; ++j)
            #pragma unroll
            for (int r = 0; r < 4; ++r) {
                float p = exp2f(sf[j][r] - 24.0f);
                sf[j][r] = p;
                l_r[r] += p;
            }
        // P: C-layout regs -> per-wave LDS -> A-layout frags
        #pragma unroll
        for (int j = 0; j < 4; ++j)
            #pragma unroll
            for (int r = 0; r < 4; ++r)
                psw[(quad * 4 + r) * 72 + j * 16 + ln15] = f2bf(sf[j][r]);

        #pragma unroll
        for (int st = 0; st < 2; ++st) {
            bf16x8 pa = *reinterpret_cast<const bf16x8*>(&psw[ln15 * 72 + st * 32 + quad * 8]);
            #pragma unroll
            for (int jd = 0; jd < 4; ++jd) {
                bf16x8 vv = *reinterpret_cast<const bf16x8*>(&Vs[(jd * 16 + ln15) * 64 + st * 32 + quad * 8]);
                oa[jd] = mfma16(pa, vv, oa[jd]);
            }
        }
    };

    const int c0 = wave * 128 + ln;        // two staging chunks per wave
    const int c1 = c0 + 64;
    const int kr0 = c0 >> 3, ko0 = (c0 & 7) * 8;
    const int kr1 = c1 >> 3, ko1 = (c1 & 7) * 8;

    for (int kblk = 0; kblk <= hi; ++kblk) {
        __syncthreads();                     // prior iter done with Ks/Vs
        llds16(kp0 + ((size_t)kblk * 64 + kr0) * Dh + ko0, &Ks[(wave * 2 + 0) * 512]);
        llds16(kp0 + ((size_t)kblk * 64 + kr1) * Dh + ko1, &Ks[(wave * 2 + 1) * 512]);
        llds16(vp0 + (size_t)kr0 * S + kblk * 64 + ko0,    &Vs[(wave * 2 + 0) * 512]);
        llds16(vp0 + (size_t)kr1 * S + kblk * 64 + ko1,    &Vs[(wave * 2 + 1) * 512]);
        __syncthreads();                     // drains vmcnt -> LDS visible
        step(qf[1], l_st[1], o_st[1], kblk == hi);
        if (kblk <= lo)
            step(qf[0], l_st[0], o_st[0], kblk == lo);
    }

    // epilogue: reduce l over the 16 column-lanes, divide, write token-major
    #pragma unroll
    for (int t = 0; t < 2; ++t) {
        const int qt = t ? hi : lo;
        float linv[4];
        #pragma unroll
        for (int r = 0; r < 4; ++r) {
            float l = l_st[t][r];
            l += __shfl_xor(l, 1, 64);
            l += __shfl_xor(l, 2, 64);
            l += __shfl_xor(l, 4, 64);
            l += __shfl_xor(l, 8, 64);
            linv[r] = 1.0f / l;
        }
        #pragma unroll
        for (int jd = 0; jd < 4; ++jd)
            #pragma unroll
            for (int r = 0; r < 4; ++r) {
                int qrow = qt * 64 + wave * 16 + quad * 4 + r;
                size_t off = ((size_t)(b * S + qrow)) * D + h * Dh + jd * 16 + ln15;
                attno[off] = f2bf(o_st[t][jd][r] * linv[r]);
            }
    }
}

// ---------------------------------------------------------------------------
// 128x128 m97-style projection GEMM + bias: attn bf16 @ WoT -> fp32 d_out
// ---------------------------------------------------------------------------
__global__ __launch_bounds__(256) void proj_gemm128(
    const u16* __restrict__ A, const u16* __restrict__ WoT,
    const float* __restrict__ bo, float* __restrict__ out)
{
    const int bm = blockIdx.x;     // 0..63
    const int bn = blockIdx.y;     // 0..7

    __shared__ u16 As[128 * 32];
    __shared__ u16 Bs[128 * 32];

    const int tid  = threadIdx.x;
    const int wave = tid >> 6, ln = tid & 63;
    const int ln15 = ln & 15, quad = ln >> 4;
    const int wm = (wave >> 1) * 64, wn = (wave & 1) * 64;

    const u16* Ab = A   + (size_t)(bm * 128) * D;
    const u16* Bb = WoT + (size_t)(bn * 128) * D;

    const int c0 = wave * 128 + ln;
    const int c1 = c0 + 64;
    const int r0 = c0 >> 2, o0 = (c0 & 3) * 8;
    const int r1 = c1 >> 2, o1 = (c1 & 3) * 8;

    f32x4 acc[4][4] = {};

    for (int k0 = 0; k0 < D; k0 += 32) {
        __syncthreads();
        llds16(Ab + (size_t)r0 * D + k0 + o0, &As[(wave * 2 + 0) * 512]);
        llds16(Ab + (size_t)r1 * D + k0 + o1, &As[(wave * 2 + 1) * 512]);
        llds16(Bb + (size_t)r0 * D + k0 + o0, &Bs[(wave * 2 + 0) * 512]);
        llds16(Bb + (size_t)r1 * D + k0 + o1, &Bs[(wave * 2 + 1) * 512]);
        __syncthreads();
        bf16x8 af[4], bfr[4];
        #pragma unroll
        for (int i = 0; i < 4; ++i)
            af[i] = *reinterpret_cast<const bf16x8*>(&As[(wm + i * 16 + ln15) * 32 + quad * 8]);
        #pragma unroll
        for (int j = 0; j < 4; ++j)
            bfr[j] = *reinterpret_cast<const bf16x8*>(&Bs[(wn + j * 16 + ln15) * 32 + quad * 8]);
        #pragma unroll
        for (int i = 0; i < 4; ++i)
            #pragma unroll
            for (int j = 0; j < 4; ++j)
                acc[i][j] = mfma16(af[i], bfr[j], acc[i][j]);
    }

    #pragma unroll
    for (int i = 0; i < 4; ++i)
        #pragma unroll
        for (int j = 0; j < 4; ++j)
            #pragma unroll
            for (int r = 0; r < 4; ++r) {
                int t   = bm * 128 + wm + i * 16 + quad * 4 + r;
                int col = bn * 128 + wn + j * 16 + ln15;
                out[(size_t)t * D + col] = acc[i][j][r] + bo[col];
            }
}

extern "C" void kernel_launch(void* const* d_in, const int* in_sizes, int n_in,
                              void* d_out, int out_size, void* d_ws, size_t ws_size,
                              hipStream_t stream) {
    const float* x  = (const float*)d_in[0];
    const float* Wq = (const float*)d_in[1];
    const float* Wk = (const float*)d_in[2];
    const float* Wv = (const float*)d_in[3];
    const float* Wo = (const float*)d_in[4];
    const float* bo = (const float*)d_in[5];
    float* out = (float*)d_out;
    u16* ws  = (u16*)d_ws;

    u16* WT   = ws;                                   // 4M u16  (8 MB)
    u16* xb   = WT + (size_t)4 * D * D;               // 8M u16  (16 MB); reused as vtb
    u16* qkvb = xb + (size_t)M * D;                   // 24M u16 (48 MB) -> 72 MB total
    u16* kb   = qkvb + (size_t)M * D;
    u16* vb   = qkvb + (size_t)2 * M * D;
    u16* vtb  = xb;                                   // xb dead after qkv_gemm128
    u16* attn = vb;                                   // vb dead after vt_transpose

    x_to_bf16   <<<dim3(M * D / (256 * 8)), 256, 0, stream>>>(x, xb);
    transpose_w <<<dim3(16, 16, 4), 256, 0, stream>>>(Wq, Wk, Wv, Wo, WT);
    qkv_gemm128 <<<dim3(64, 24),    256, 0, stream>>>(xb, WT, qkvb);
    vt_transpose<<<dim3(32, 64),    256, 0, stream>>>(vb, vtb);
    attn_kernel <<<dim3(16, 64),    256, 0, stream>>>(qkvb, kb, vtb, attn);
    proj_gemm128<<<dim3(64, 8),     256, 0, stream>>>(attn, WT + (size_t)3 * D * D, bo, out);
}

// Round 7
// 281.101 us; speedup vs baseline: 1.7542x; 1.0829x over previous
//
#include <hip/hip_runtime.h>
#include <hip/hip_bf16.h>

#define DEV __device__ __forceinline__

typedef unsigned short u16;
typedef unsigned int u32;
typedef __bf16 bf16x8 __attribute__((ext_vector_type(8)));
typedef float f32x4 __attribute__((ext_vector_type(4)));

static constexpr int S   = 2048;
static constexpr int D   = 1024;
static constexpr int H   = 16;
static constexpr int Dh  = 64;
static constexpr int B_  = 4;
static constexpr int M   = B_ * S;   // 8192 tokens

DEV u16 f2bf(float f) {
    __hip_bfloat16 h = __float2bfloat16(f);
    union { __hip_bfloat16 h; u16 u; } cv; cv.h = h; return cv.u;
}
DEV float bf2f(u16 u) {
    union { u16 u; __hip_bfloat16 h; } cv; cv.u = u; return __bfloat162float(cv.h);
}
DEV f32x4 mfma16(bf16x8 a, bf16x8 b, f32x4 c) {
    return __builtin_amdgcn_mfma_f32_16x16x32_bf16(a, b, c, 0, 0, 0);
}
// async global->LDS, 16B per lane; lds dest = wave-uniform base + lane*16
DEV void llds16(const u16* g, u16* l) {
    __builtin_amdgcn_global_load_lds(
        (const __attribute__((address_space(1))) u32*)g,
        (__attribute__((address_space(3))) u32*)l, 16, 0, 0);
}
// load 8 contiguous fp32, round to 8 bf16
DEV bf16x8 ld8f(const float* p) {
    const f32x4* q = reinterpret_cast<const f32x4*>(p);
    f32x4 a = q[0], b = q[1];
    union { u16 u[8]; bf16x8 v; } r;
    r.u[0] = f2bf(a[0]); r.u[1] = f2bf(a[1]); r.u[2] = f2bf(a[2]); r.u[3] = f2bf(a[3]);
    r.u[4] = f2bf(b[0]); r.u[5] = f2bf(b[1]); r.u[6] = f2bf(b[2]); r.u[7] = f2bf(b[3]);
    return r.v;
}

// ---------------------------------------------------------------------------
// x fp32 -> bf16 (one-shot)
// ---------------------------------------------------------------------------
__global__ __launch_bounds__(256) void x_to_bf16(
    const float* __restrict__ x, u16* __restrict__ xb)
{
    size_t i = ((size_t)blockIdx.x * 256 + threadIdx.x) * 8;
    *reinterpret_cast<bf16x8*>(xb + i) = ld8f(x + i);
}

// ---------------------------------------------------------------------------
// Transpose + bf16-convert the 4 fp32 weight matrices [K][N] -> bf16 [N][K]
// ---------------------------------------------------------------------------
__global__ __launch_bounds__(256) void transpose_w(
    const float* __restrict__ Wq, const float* __restrict__ Wk,
    const float* __restrict__ Wv, const float* __restrict__ Wo,
    u16* __restrict__ WT)
{
    const float* src = blockIdx.z == 0 ? Wq : blockIdx.z == 1 ? Wk
                     : blockIdx.z == 2 ? Wv : Wo;
    u16* dst = WT + (size_t)blockIdx.z * D * D;
    __shared__ u16 T[64 * 72];
    const int k0 = blockIdx.x * 64, n0 = blockIdx.y * 64;
    const int tid = threadIdx.x;
    for (int c = tid; c < 512; c += 256) {
        int r = c >> 3, cc = (c & 7) << 3;
        *reinterpret_cast<bf16x8*>(&T[r * 72 + cc]) =
            ld8f(&src[(size_t)(k0 + r) * D + n0 + cc]);
    }
    __syncthreads();
    for (int c = tid; c < 512; c += 256) {
        int r = c >> 3, cc = (c & 7) << 3;
        u16 tmp[8];
        #pragma unroll
        for (int i = 0; i < 8; ++i) tmp[i] = T[(cc + i) * 72 + r];
        *reinterpret_cast<bf16x8*>(&dst[(size_t)(n0 + r) * D + k0 + cc]) =
            *reinterpret_cast<const bf16x8*>(tmp);
    }
}

// ---------------------------------------------------------------------------
// 128x128 m97-style GEMM: A bf16 [M][1024] x WT bf16 [3072][1024] -> qkv
// ---------------------------------------------------------------------------
__global__ __launch_bounds__(256) void qkv_gemm128(
    const u16* __restrict__ A, const u16* __restrict__ WT,
    u16* __restrict__ qkv)
{
    const int bm = blockIdx.x;     // 0..63
    const int bn = blockIdx.y;     // 0..23

    __shared__ u16 As[128 * 32];
    __shared__ u16 Bs[128 * 32];

    const int tid  = threadIdx.x;
    const int wave = tid >> 6, ln = tid & 63;
    const int ln15 = ln & 15, quad = ln >> 4;
    const int wm = (wave >> 1) * 64, wn = (wave & 1) * 64;

    const u16* Ab = A  + (size_t)(bm * 128) * D;
    const u16* Bb = WT + (size_t)(bn * 128) * D;

    const int c0  = wave * 128 + ln;
    const int c1  = c0 + 64;
    const int r0  = c0 >> 2, o0 = (c0 & 3) * 8;
    const int r1  = c1 >> 2, o1 = (c1 & 3) * 8;

    f32x4 acc[4][4] = {};

    for (int k0 = 0; k0 < D; k0 += 32) {
        __syncthreads();
        llds16(Ab + (size_t)r0 * D + k0 + o0, &As[(wave * 2 + 0) * 512]);
        llds16(Ab + (size_t)r1 * D + k0 + o1, &As[(wave * 2 + 1) * 512]);
        llds16(Bb + (size_t)r0 * D + k0 + o0, &Bs[(wave * 2 + 0) * 512]);
        llds16(Bb + (size_t)r1 * D + k0 + o1, &Bs[(wave * 2 + 1) * 512]);
        __syncthreads();
        bf16x8 af[4], bfr[4];
        #pragma unroll
        for (int i = 0; i < 4; ++i)
            af[i] = *reinterpret_cast<const bf16x8*>(&As[(wm + i * 16 + ln15) * 32 + quad * 8]);
        #pragma unroll
        for (int j = 0; j < 4; ++j)
            bfr[j] = *reinterpret_cast<const bf16x8*>(&Bs[(wn + j * 16 + ln15) * 32 + quad * 8]);
        #pragma unroll
        for (int i = 0; i < 4; ++i)
            #pragma unroll
            for (int j = 0; j < 4; ++j)
                acc[i][j] = mfma16(af[i], bfr[j], acc[i][j]);
    }

    const int matn = bn >> 3;                       // 0=Q 1=K 2=V (wave-uniform)
    u16* outp = qkv + (size_t)matn * M * D;
    #pragma unroll
    for (int i = 0; i < 4; ++i)
        #pragma unroll
        for (int j = 0; j < 4; ++j)
            #pragma unroll
            for (int r = 0; r < 4; ++r) {
                int t = bm * 128 + wm + i * 16 + quad * 4 + r;
                int b = t >> 11, s = t & (S - 1);
                int n = (bn & 7) * 128 + wn + j * 16 + ln15;   // 0..1023 in-mat
                int head = n >> 6, dh = n & 63;
                outp[(((size_t)(b * H + head)) * S + s) * Dh + dh] = f2bf(acc[i][j][r]);
            }
}

// ---------------------------------------------------------------------------
// V [bh][s][dh] -> Vt [bh][dh][s]  (one-shot, coalesced via LDS tile)
// ---------------------------------------------------------------------------
__global__ __launch_bounds__(256) void vt_transpose(
    const u16* __restrict__ v, u16* __restrict__ vtout)
{
    const int st = blockIdx.x;   // s-tile 0..31
    const int bh = blockIdx.y;   // 0..63
    __shared__ u16 T[64 * 72];
    const u16* src = v + ((size_t)bh * S + st * 64) * Dh;
    u16* dst = vtout + (size_t)bh * Dh * S + st * 64;
    const int tid = threadIdx.x;
    for (int c = tid; c < 512; c += 256) {
        int r = c >> 3, cc = (c & 7) << 3;
        *reinterpret_cast<bf16x8*>(&T[r * 72 + cc]) =
            *reinterpret_cast<const bf16x8*>(&src[r * 64 + cc]);
    }
    __syncthreads();
    for (int c = tid; c < 512; c += 256) {
        int r = c >> 3, cc = (c & 7) << 3;
        u16 tmp[8];
        #pragma unroll
        for (int i = 0; i < 8; ++i) tmp[i] = T[(cc + i) * 72 + r];
        *reinterpret_cast<bf16x8*>(&dst[(size_t)r * S + cc]) =
            *reinterpret_cast<const bf16x8*>(tmp);
    }
}

// ---------------------------------------------------------------------------
// Flash attention (causal). 4 q-tiles per block {i,15-i,16+i,31-i} sharing
// each K/V stage (2.3 steps/stage vs 1.4). Fixed-offset softmax
// (p = 2^(s-24), unnormalized O, one epilogue reduce).
// K/V LDS layout XOR-swizzled BY CHUNK: physical chunk p holds conceptual
// chunk (p&7)^(row&7) -> fragment ds_read_b128 uses all 32 banks (2-way max);
// gather side of global_load_lds applies the inverse permutation (stays
// within one 128B row -> still coalesced).
// ---------------------------------------------------------------------------
__global__ __launch_bounds__(256) void attn_kernel(
    const u16* __restrict__ qbuf, const u16* __restrict__ kbuf,
    const u16* __restrict__ vt, u16* __restrict__ attno)
{
    const int i  = blockIdx.x;          // 0..7
    const int bh = blockIdx.y;          // 0..63
    const int b = bh >> 4, h = bh & 15;
    const int qt[4] = {i, 15 - i, 16 + i, 31 - i};

    __shared__ u16 Ks[64 * 64];
    __shared__ u16 Vs[64 * 64];         // [dh][kpos], chunk-swizzled
    __shared__ u16 Ps[4][16 * 72];      // per-wave P tile, stride 72

    const int tid  = threadIdx.x;
    const int wave = tid >> 6, ln = tid & 63;
    const int ln15 = ln & 15, quad = ln >> 4;
    const int swz  = ln15 & 7;          // row-phase for swizzled frag reads

    const u16* kp0 = kbuf + (size_t)bh * S * Dh;
    const u16* vp0 = vt   + (size_t)bh * Dh * S;

    // Q fragments for all 4 tiles, pre-scaled by 0.125*log2e (plain staging)
    bf16x8 qf[4][2];
    #pragma unroll
    for (int t = 0; t < 4; ++t) {
        const u16* qp = qbuf + ((size_t)bh * S + qt[t] * 64) * Dh;
        for (int c = tid; c < 512; c += 256) {
            int r = c >> 3, cc = (c & 7) << 3;
            *reinterpret_cast<bf16x8*>(&Ks[r * 64 + cc]) =
                *reinterpret_cast<const bf16x8*>(&qp[r * 64 + cc]);
        }
        __syncthreads();
        #pragma unroll
        for (int st = 0; st < 2; ++st) {
            union { bf16x8 v; u16 u[8]; } in, ot;
            in.v = *reinterpret_cast<const bf16x8*>(&Ks[(wave * 16 + ln15) * 64 + st * 32 + quad * 8]);
            #pragma unroll
            for (int k = 0; k < 8; ++k) ot.u[k] = f2bf(bf2f(in.u[k]) * 0.18033688f);
            qf[t][st] = ot.v;
        }
        __syncthreads();
    }

    float l_st[4][4] = {};
    f32x4 o_st[4][4] = {};

    u16* psw = &Ps[wave][0];
    const int lrow = wave * 16 + quad * 4;

    auto step = [&](int t, bool domask) {
        const bf16x8* qa = qf[t];
        float* l_r = l_st[t];
        f32x4* oa = o_st[t];
        f32x4 sf[4] = {};
        #pragma unroll
        for (int j = 0; j < 4; ++j) {
            bf16x8 k0 = *reinterpret_cast<const bf16x8*>(
                &Ks[(j * 16 + ln15) * 64 + ((0 * 4 + quad) ^ swz) * 8]);
            bf16x8 k1 = *reinterpret_cast<const bf16x8*>(
                &Ks[(j * 16 + ln15) * 64 + ((1 * 4 + quad) ^ swz) * 8]);
            sf[j] = mfma16(qa[0], k0, sf[j]);
            sf[j] = mfma16(qa[1], k1, sf[j]);
        }
        if (domask) {
            #pragma unroll
            for (int j = 0; j < 4; ++j) {
                int kg = j * 16 + ln15;
                #pragma unroll
                for (int r = 0; r < 4; ++r)
                    if (kg > lrow + r) sf[j][r] = -3e38f;
            }
        }
        #pragma unroll
        for (int j = 0; j < 4; ++j)
            #pragma unroll
            for (int r = 0; r < 4; ++r) {
                float p = exp2f(sf[j][r] - 24.0f);
                sf[j][r] = p;
                l_r[r] += p;
            }
        // P: C-layout regs -> per-wave LDS (stride 72) -> A-layout frags
        #pragma unroll
        for (int j = 0; j < 4; ++j)
            #pragma unroll
            for (int r = 0; r < 4; ++r)
                psw[(quad * 4 + r) * 72 + j * 16 + ln15] = f2bf(sf[j][r]);

        #pragma unroll
        for (int st = 0; st < 2; ++st) {
            bf16x8 pa = *reinterpret_cast<const bf16x8*>(&psw[ln15 * 72 + st * 32 + quad * 8]);
            #pragma unroll
            for (int jd = 0; jd < 4; ++jd) {
                bf16x8 vv = *reinterpret_cast<const bf16x8*>(
                    &Vs[(jd * 16 + ln15) * 64 + ((st * 4 + quad) ^ swz) * 8]);
                oa[jd] = mfma16(pa, vv, oa[jd]);
            }
        }
    };

    // staging: physical chunk p = c*; row r = p>>3, conceptual chunk (p&7)^(r&7)
    const int c0 = wave * 128 + ln;
    const int c1 = c0 + 64;
    const int kr0 = c0 >> 3, ko0 = (((c0 & 7) ^ (kr0 & 7)) * 8);
    const int kr1 = c1 >> 3, ko1 = (((c1 & 7) ^ (kr1 & 7)) * 8);

    const int nstage = qt[3] + 1;       // 32 - i
    for (int kblk = 0; kblk < nstage; ++kblk) {
        __syncthreads();                     // prior iter done with Ks/Vs
        llds16(kp0 + ((size_t)kblk * 64 + kr0) * Dh + ko0, &Ks[(wave * 2 + 0) * 512]);
        llds16(kp0 + ((size_t)kblk * 64 + kr1) * Dh + ko1, &Ks[(wave * 2 + 1) * 512]);
        llds16(vp0 + (size_t)kr0 * S + kblk * 64 + ko0,    &Vs[(wave * 2 + 0) * 512]);
        llds16(vp0 + (size_t)kr1 * S + kblk * 64 + ko1,    &Vs[(wave * 2 + 1) * 512]);
        __syncthreads();                     // drains vmcnt -> LDS visible
        step(3, kblk == qt[3]);
        if (kblk <= qt[2]) step(2, kblk == qt[2]);
        if (kblk <= qt[1]) step(1, kblk == qt[1]);
        if (kblk <= qt[0]) step(0, kblk == qt[0]);
    }

    // epilogue: reduce l over the 16 column-lanes, divide, write token-major
    #pragma unroll
    for (int t = 0; t < 4; ++t) {
        float linv[4];
        #pragma unroll
        for (int r = 0; r < 4; ++r) {
            float l = l_st[t][r];
            l += __shfl_xor(l, 1, 64);
            l += __shfl_xor(l, 2, 64);
            l += __shfl_xor(l, 4, 64);
            l += __shfl_xor(l, 8, 64);
            linv[r] = 1.0f / l;
        }
        #pragma unroll
        for (int jd = 0; jd < 4; ++jd)
            #pragma unroll
            for (int r = 0; r < 4; ++r) {
                int qrow = qt[t] * 64 + wave * 16 + quad * 4 + r;
                size_t off = ((size_t)(b * S + qrow)) * D + h * Dh + jd * 16 + ln15;
                attno[off] = f2bf(o_st[t][jd][r] * linv[r]);
            }
    }
}

// ---------------------------------------------------------------------------
// 128x128 m97-style projection GEMM + bias: attn bf16 @ WoT -> fp32 d_out
// ---------------------------------------------------------------------------
__global__ __launch_bounds__(256) void proj_gemm128(
    const u16* __restrict__ A, const u16* __restrict__ WoT,
    const float* __restrict__ bo, float* __restrict__ out)
{
    const int bm = blockIdx.x;     // 0..63
    const int bn = blockIdx.y;     // 0..7

    __shared__ u16 As[128 * 32];
    __shared__ u16 Bs[128 * 32];

    const int tid  = threadIdx.x;
    const int wave = tid >> 6, ln = tid & 63;
    const int ln15 = ln & 15, quad = ln >> 4;
    const int wm = (wave >> 1) * 64, wn = (wave & 1) * 64;

    const u16* Ab = A   + (size_t)(bm * 128) * D;
    const u16* Bb = WoT + (size_t)(bn * 128) * D;

    const int c0 = wave * 128 + ln;
    const int c1 = c0 + 64;
    const int r0 = c0 >> 2, o0 = (c0 & 3) * 8;
    const int r1 = c1 >> 2, o1 = (c1 & 3) * 8;

    f32x4 acc[4][4] = {};

    for (int k0 = 0; k0 < D; k0 += 32) {
        __syncthreads();
        llds16(Ab + (size_t)r0 * D + k0 + o0, &As[(wave * 2 + 0) * 512]);
        llds16(Ab + (size_t)r1 * D + k0 + o1, &As[(wave * 2 + 1) * 512]);
        llds16(Bb + (size_t)r0 * D + k0 + o0, &Bs[(wave * 2 + 0) * 512]);
        llds16(Bb + (size_t)r1 * D + k0 + o1, &Bs[(wave * 2 + 1) * 512]);
        __syncthreads();
        bf16x8 af[4], bfr[4];
        #pragma unroll
        for (int i = 0; i < 4; ++i)
            af[i] = *reinterpret_cast<const bf16x8*>(&As[(wm + i * 16 + ln15) * 32 + quad * 8]);
        #pragma unroll
        for (int j = 0; j < 4; ++j)
            bfr[j] = *reinterpret_cast<const bf16x8*>(&Bs[(wn + j * 16 + ln15) * 32 + quad * 8]);
        #pragma unroll
        for (int i = 0; i < 4; ++i)
            #pragma unroll
            for (int j = 0; j < 4; ++j)
                acc[i][j] = mfma16(af[i], bfr[j], acc[i][j]);
    }

    #pragma unroll
    for (int i = 0; i < 4; ++i)
        #pragma unroll
        for (int j = 0; j < 4; ++j)
            #pragma unroll
            for (int r = 0; r < 4; ++r) {
                int t   = bm * 128 + wm + i * 16 + quad * 4 + r;
                int col = bn * 128 + wn + j * 16 + ln15;
                out[(size_t)t * D + col] = acc[i][j][r] + bo[col];
            }
}

extern "C" void kernel_launch(void* const* d_in, const int* in_sizes, int n_in,
                              void* d_out, int out_size, void* d_ws, size_t ws_size,
                              hipStream_t stream) {
    const float* x  = (const float*)d_in[0];
    const float* Wq = (const float*)d_in[1];
    const float* Wk = (const float*)d_in[2];
    const float* Wv = (const float*)d_in[3];
    const float* Wo = (const float*)d_in[4];
    const float* bo = (const float*)d_in[5];
    float* out = (float*)d_out;
    u16* ws  = (u16*)d_ws;

    u16* WT   = ws;                                   // 4M u16  (8 MB)
    u16* xb   = WT + (size_t)4 * D * D;               // 8M u16  (16 MB); reused as vtb
    u16* qkvb = xb + (size_t)M * D;                   // 24M u16 (48 MB) -> 72 MB total
    u16* kb   = qkvb + (size_t)M * D;
    u16* vb   = qkvb + (size_t)2 * M * D;
    u16* vtb  = xb;                                   // xb dead after qkv_gemm128
    u16* attn = vb;                                   // vb dead after vt_transpose

    x_to_bf16   <<<dim3(M * D / (256 * 8)), 256, 0, stream>>>(x, xb);
    transpose_w <<<dim3(16, 16, 4), 256, 0, stream>>>(Wq, Wk, Wv, Wo, WT);
    qkv_gemm128 <<<dim3(64, 24),    256, 0, stream>>>(xb, WT, qkvb);
    vt_transpose<<<dim3(32, 64),    256, 0, stream>>>(vb, vtb);
    attn_kernel <<<dim3(8, 64),     256, 0, stream>>>(qkvb, kb, vtb, attn);
    proj_gemm128<<<dim3(64, 8),     256, 0, stream>>>(attn, WT + (size_t)3 * D * D, bo, out);
}

// Round 8
// 280.288 us; speedup vs baseline: 1.7593x; 1.0029x over previous
//
#include <hip/hip_runtime.h>
#include <hip/hip_bf16.h>

#define DEV __device__ __forceinline__

typedef unsigned short u16;
typedef unsigned int u32;
typedef __bf16 bf16x8 __attribute__((ext_vector_type(8)));
typedef float f32x4 __attribute__((ext_vector_type(4)));

static constexpr int S   = 2048;
static constexpr int D   = 1024;
static constexpr int H   = 16;
static constexpr int Dh  = 64;
static constexpr int B_  = 4;
static constexpr int M   = B_ * S;   // 8192 tokens

DEV u16 f2bf(float f) {
    __hip_bfloat16 h = __float2bfloat16(f);
    union { __hip_bfloat16 h; u16 u; } cv; cv.h = h; return cv.u;
}
DEV float bf2f(u16 u) {
    union { u16 u; __hip_bfloat16 h; } cv; cv.u = u; return __bfloat162float(cv.h);
}
DEV f32x4 mfma16(bf16x8 a, bf16x8 b, f32x4 c) {
    return __builtin_amdgcn_mfma_f32_16x16x32_bf16(a, b, c, 0, 0, 0);
}
// async global->LDS, 16B per lane; lds dest = wave-uniform base + lane*16
DEV void llds16(const u16* g, u16* l) {
    __builtin_amdgcn_global_load_lds(
        (const __attribute__((address_space(1))) u32*)g,
        (__attribute__((address_space(3))) u32*)l, 16, 0, 0);
}
// load 8 contiguous fp32, round to 8 bf16
DEV bf16x8 ld8f(const float* p) {
    const f32x4* q = reinterpret_cast<const f32x4*>(p);
    f32x4 a = q[0], b = q[1];
    union { u16 u[8]; bf16x8 v; } r;
    r.u[0] = f2bf(a[0]); r.u[1] = f2bf(a[1]); r.u[2] = f2bf(a[2]); r.u[3] = f2bf(a[3]);
    r.u[4] = f2bf(b[0]); r.u[5] = f2bf(b[1]); r.u[6] = f2bf(b[2]); r.u[7] = f2bf(b[3]);
    return r.v;
}

// ---------------------------------------------------------------------------
// x fp32 -> bf16 (one-shot)
// ---------------------------------------------------------------------------
__global__ __launch_bounds__(256) void x_to_bf16(
    const float* __restrict__ x, u16* __restrict__ xb)
{
    size_t i = ((size_t)blockIdx.x * 256 + threadIdx.x) * 8;
    *reinterpret_cast<bf16x8*>(xb + i) = ld8f(x + i);
}

// ---------------------------------------------------------------------------
// Transpose + bf16-convert the 4 fp32 weight matrices [K][N] -> bf16 [N][K]
// ---------------------------------------------------------------------------
__global__ __launch_bounds__(256) void transpose_w(
    const float* __restrict__ Wq, const float* __restrict__ Wk,
    const float* __restrict__ Wv, const float* __restrict__ Wo,
    u16* __restrict__ WT)
{
    const float* src = blockIdx.z == 0 ? Wq : blockIdx.z == 1 ? Wk
                     : blockIdx.z == 2 ? Wv : Wo;
    u16* dst = WT + (size_t)blockIdx.z * D * D;
    __shared__ u16 T[64 * 72];
    const int k0 = blockIdx.x * 64, n0 = blockIdx.y * 64;
    const int tid = threadIdx.x;
    for (int c = tid; c < 512; c += 256) {
        int r = c >> 3, cc = (c & 7) << 3;
        *reinterpret_cast<bf16x8*>(&T[r * 72 + cc]) =
            ld8f(&src[(size_t)(k0 + r) * D + n0 + cc]);
    }
    __syncthreads();
    for (int c = tid; c < 512; c += 256) {
        int r = c >> 3, cc = (c & 7) << 3;
        u16 tmp[8];
        #pragma unroll
        for (int i = 0; i < 8; ++i) tmp[i] = T[(cc + i) * 72 + r];
        *reinterpret_cast<bf16x8*>(&dst[(size_t)(n0 + r) * D + k0 + cc]) =
            *reinterpret_cast<const bf16x8*>(tmp);
    }
}

// ---------------------------------------------------------------------------
// 128x128 m97-style GEMM: A bf16 [M][1024] x WT bf16 [3072][1024].
// Q,K written to qkv [mat][b*H+h][s][dh]; V transposed IN-KERNEL via an LDS
// tile and written straight to Vt [b*H+h][dh][s] (fuses old vt_transpose).
// ---------------------------------------------------------------------------
__global__ __launch_bounds__(256) void qkv_gemm128(
    const u16* __restrict__ A, const u16* __restrict__ WT,
    u16* __restrict__ qkv, u16* __restrict__ vtb)
{
    const int bm = blockIdx.x;     // 0..63
    const int bn = blockIdx.y;     // 0..23

    __shared__ u16 As[128 * 32];
    __shared__ u16 Bs[128 * 32];
    __shared__ u16 Tt[64 * 136];   // V-transpose tile (matn==2 only)

    const int tid  = threadIdx.x;
    const int wave = tid >> 6, ln = tid & 63;
    const int ln15 = ln & 15, quad = ln >> 4;
    const int wm = (wave >> 1) * 64, wn = (wave & 1) * 64;

    const u16* Ab = A  + (size_t)(bm * 128) * D;
    const u16* Bb = WT + (size_t)(bn * 128) * D;

    const int c0  = wave * 128 + ln;
    const int c1  = c0 + 64;
    const int r0  = c0 >> 2, o0 = (c0 & 3) * 8;
    const int r1  = c1 >> 2, o1 = (c1 & 3) * 8;

    f32x4 acc[4][4] = {};

    for (int k0 = 0; k0 < D; k0 += 32) {
        __syncthreads();
        llds16(Ab + (size_t)r0 * D + k0 + o0, &As[(wave * 2 + 0) * 512]);
        llds16(Ab + (size_t)r1 * D + k0 + o1, &As[(wave * 2 + 1) * 512]);
        llds16(Bb + (size_t)r0 * D + k0 + o0, &Bs[(wave * 2 + 0) * 512]);
        llds16(Bb + (size_t)r1 * D + k0 + o1, &Bs[(wave * 2 + 1) * 512]);
        __syncthreads();
        bf16x8 af[4], bfr[4];
        #pragma unroll
        for (int i = 0; i < 4; ++i)
            af[i] = *reinterpret_cast<const bf16x8*>(&As[(wm + i * 16 + ln15) * 32 + quad * 8]);
        #pragma unroll
        for (int j = 0; j < 4; ++j)
            bfr[j] = *reinterpret_cast<const bf16x8*>(&Bs[(wn + j * 16 + ln15) * 32 + quad * 8]);
        #pragma unroll
        for (int i = 0; i < 4; ++i)
            #pragma unroll
            for (int j = 0; j < 4; ++j)
                acc[i][j] = mfma16(af[i], bfr[j], acc[i][j]);
    }

    const int matn = bn >> 3;                       // 0=Q 1=K 2=V (block-uniform)
    if (matn < 2) {
        u16* outp = qkv + (size_t)matn * M * D;
        #pragma unroll
        for (int i = 0; i < 4; ++i)
            #pragma unroll
            for (int j = 0; j < 4; ++j)
                #pragma unroll
                for (int r = 0; r < 4; ++r) {
                    int t = bm * 128 + wm + i * 16 + quad * 4 + r;
                    int b = t >> 11, s = t & (S - 1);
                    int n = (bn & 7) * 128 + wn + j * 16 + ln15;   // 0..1023
                    int head = n >> 6, dh = n & 63;
                    outp[(((size_t)(b * H + head)) * S + s) * Dh + dh] = f2bf(acc[i][j][r]);
                }
    } else {
        // V: LDS transpose -> Vt [bh][dh][s] (two heads per block, one at a time)
        const int t0 = bm * 128, b = t0 >> 11, s0 = t0 & (S - 1);
        #pragma unroll
        for (int h2 = 0; h2 < 2; ++h2) {
            __syncthreads();
            if ((wn == 0) == (h2 == 0)) {   // wn==0 waves hold cols 0..63 = head 0
                #pragma unroll
                for (int i = 0; i < 4; ++i)
                    #pragma unroll
                    for (int j = 0; j < 4; ++j)
                        #pragma unroll
                        for (int r = 0; r < 4; ++r) {
                            int sl = wm + i * 16 + quad * 4 + r;   // 0..127
                            int dh = j * 16 + ln15;                // 0..63
                            Tt[dh * 136 + sl] = f2bf(acc[i][j][r]);
                        }
            }
            __syncthreads();
            const int bh = b * H + (bn & 7) * 2 + h2;
            u16* dst = vtb + (size_t)bh * Dh * S + s0;
            for (int c = tid; c < 1024; c += 256) {
                int r = c >> 4, cc = (c & 15) * 8;
                *reinterpret_cast<bf16x8*>(&dst[(size_t)r * S + cc]) =
                    *reinterpret_cast<const bf16x8*>(&Tt[r * 136 + cc]);
            }
        }
    }
}

// ---------------------------------------------------------------------------
// Flash attention (causal). 4 q-tiles per block {i,15-i,16+i,31-i}.
// Double-buffered K/V stages (prefetch next while computing current) +
// K/V fragments hoisted to registers once per stage (16 ds_read_b128/stage
// instead of up to 64). Fixed-offset softmax (p=2^(s-24), unnormalized O).
// K/V LDS chunk-XOR-swizzled (round-7 scheme, conflicts 20.5M -> 1.3M).
// ---------------------------------------------------------------------------
__global__ __launch_bounds__(256) void attn_kernel(
    const u16* __restrict__ qbuf, const u16* __restrict__ kbuf,
    const u16* __restrict__ vt, u16* __restrict__ attno)
{
    const int i  = blockIdx.x;          // 0..7
    const int bh = blockIdx.y;          // 0..63
    const int b = bh >> 4, h = bh & 15;
    const int qt[4] = {i, 15 - i, 16 + i, 31 - i};

    __shared__ u16 Ks[2][64 * 64];
    __shared__ u16 Vs[2][64 * 64];      // [dh][kpos], chunk-swizzled
    __shared__ u16 Ps[4][16 * 72];      // per-wave P tile, stride 72

    const int tid  = threadIdx.x;
    const int wave = tid >> 6, ln = tid & 63;
    const int ln15 = ln & 15, quad = ln >> 4;
    const int swz  = ln15 & 7;

    const u16* kp0 = kbuf + (size_t)bh * S * Dh;
    const u16* vp0 = vt   + (size_t)bh * Dh * S;

    // Q fragments for all 4 tiles, pre-scaled by 0.125*log2e (Ks[0] scratch)
    bf16x8 qf[4][2];
    #pragma unroll
    for (int t = 0; t < 4; ++t) {
        const u16* qp = qbuf + ((size_t)bh * S + qt[t] * 64) * Dh;
        for (int c = tid; c < 512; c += 256) {
            int r = c >> 3, cc = (c & 7) << 3;
            *reinterpret_cast<bf16x8*>(&Ks[0][r * 64 + cc]) =
                *reinterpret_cast<const bf16x8*>(&qp[r * 64 + cc]);
        }
        __syncthreads();
        #pragma unroll
        for (int st = 0; st < 2; ++st) {
            union { bf16x8 v; u16 u[8]; } in, ot;
            in.v = *reinterpret_cast<const bf16x8*>(&Ks[0][(wave * 16 + ln15) * 64 + st * 32 + quad * 8]);
            #pragma unroll
            for (int k = 0; k < 8; ++k) ot.u[k] = f2bf(bf2f(in.u[k]) * 0.18033688f);
            qf[t][st] = ot.v;
        }
        __syncthreads();
    }

    float l_st[4][4] = {};
    f32x4 o_st[4][4] = {};

    u16* psw = &Ps[wave][0];
    const int lrow = wave * 16 + quad * 4;

    // staging coords: physical chunk p, row r=p>>3, conceptual chunk (p&7)^(r&7)
    const int c0 = wave * 128 + ln;
    const int c1 = c0 + 64;
    const int kr0 = c0 >> 3, ko0 = (((c0 & 7) ^ (kr0 & 7)) * 8);
    const int kr1 = c1 >> 3, ko1 = (((c1 & 7) ^ (kr1 & 7)) * 8);

    auto stage = [&](int kblk, int buf) {
        llds16(kp0 + ((size_t)kblk * 64 + kr0) * Dh + ko0, &Ks[buf][(wave * 2 + 0) * 512]);
        llds16(kp0 + ((size_t)kblk * 64 + kr1) * Dh + ko1, &Ks[buf][(wave * 2 + 1) * 512]);
        llds16(vp0 + (size_t)kr0 * S + kblk * 64 + ko0,    &Vs[buf][(wave * 2 + 0) * 512]);
        llds16(vp0 + (size_t)kr1 * S + kblk * 64 + ko1,    &Vs[buf][(wave * 2 + 1) * 512]);
    };

    bf16x8 kf[2][4], vf[2][4];          // per-stage register fragments

    auto step = [&](int t, bool domask) {
        const bf16x8* qa = qf[t];
        float* l_r = l_st[t];
        f32x4* oa = o_st[t];
        f32x4 sf[4] = {};
        #pragma unroll
        for (int j = 0; j < 4; ++j) {
            sf[j] = mfma16(qa[0], kf[0][j], sf[j]);
            sf[j] = mfma16(qa[1], kf[1][j], sf[j]);
        }
        if (domask) {
            #pragma unroll
            for (int j = 0; j < 4; ++j) {
                int kg = j * 16 + ln15;
                #pragma unroll
                for (int r = 0; r < 4; ++r)
                    if (kg > lrow + r) sf[j][r] = -3e38f;
            }
        }
        #pragma unroll
        for (int j = 0; j < 4; ++j)
            #pragma unroll
            for (int r = 0; r < 4; ++r) {
                float p = exp2f(sf[j][r] - 24.0f);
                sf[j][r] = p;
                l_r[r] += p;
            }
        #pragma unroll
        for (int j = 0; j < 4; ++j)
            #pragma unroll
            for (int r = 0; r < 4; ++r)
                psw[(quad * 4 + r) * 72 + j * 16 + ln15] = f2bf(sf[j][r]);

        #pragma unroll
        for (int st = 0; st < 2; ++st) {
            bf16x8 pa = *reinterpret_cast<const bf16x8*>(&psw[ln15 * 72 + st * 32 + quad * 8]);
            #pragma unroll
            for (int jd = 0; jd < 4; ++jd)
                oa[jd] = mfma16(pa, vf[st][jd], oa[jd]);
        }
    };

    const int nstage = qt[3] + 1;       // 32 - i
    stage(0, 0);
    int cur = 0;
    for (int kblk = 0; kblk < nstage; ++kblk) {
        __syncthreads();                     // drains prefetch for cur buffer
        if (kblk + 1 < nstage) stage(kblk + 1, cur ^ 1);
        // hoist K/V fragments for this stage into registers
        #pragma unroll
        for (int st = 0; st < 2; ++st)
            #pragma unroll
            for (int j = 0; j < 4; ++j) {
                kf[st][j] = *reinterpret_cast<const bf16x8*>(
                    &Ks[cur][(j * 16 + ln15) * 64 + ((st * 4 + quad) ^ swz) * 8]);
                vf[st][j] = *reinterpret_cast<const bf16x8*>(
                    &Vs[cur][(j * 16 + ln15) * 64 + ((st * 4 + quad) ^ swz) * 8]);
            }
        step(3, kblk == qt[3]);
        if (kblk <= qt[2]) step(2, kblk == qt[2]);
        if (kblk <= qt[1]) step(1, kblk == qt[1]);
        if (kblk <= qt[0]) step(0, kblk == qt[0]);
        cur ^= 1;
    }

    // epilogue: reduce l over the 16 column-lanes, divide, write token-major
    #pragma unroll
    for (int t = 0; t < 4; ++t) {
        float linv[4];
        #pragma unroll
        for (int r = 0; r < 4; ++r) {
            float l = l_st[t][r];
            l += __shfl_xor(l, 1, 64);
            l += __shfl_xor(l, 2, 64);
            l += __shfl_xor(l, 4, 64);
            l += __shfl_xor(l, 8, 64);
            linv[r] = 1.0f / l;
        }
        #pragma unroll
        for (int jd = 0; jd < 4; ++jd)
            #pragma unroll
            for (int r = 0; r < 4; ++r) {
                int qrow = qt[t] * 64 + wave * 16 + quad * 4 + r;
                size_t off = ((size_t)(b * S + qrow)) * D + h * Dh + jd * 16 + ln15;
                attno[off] = f2bf(o_st[t][jd][r] * linv[r]);
            }
    }
}

// ---------------------------------------------------------------------------
// 128x128 m97-style projection GEMM + bias: attn bf16 @ WoT -> fp32 d_out
// ---------------------------------------------------------------------------
__global__ __launch_bounds__(256) void proj_gemm128(
    const u16* __restrict__ A, const u16* __restrict__ WoT,
    const float* __restrict__ bo, float* __restrict__ out)
{
    const int bm = blockIdx.x;     // 0..63
    const int bn = blockIdx.y;     // 0..7

    __shared__ u16 As[128 * 32];
    __shared__ u16 Bs[128 * 32];

    const int tid  = threadIdx.x;
    const int wave = tid >> 6, ln = tid & 63;
    const int ln15 = ln & 15, quad = ln >> 4;
    const int wm = (wave >> 1) * 64, wn = (wave & 1) * 64;

    const u16* Ab = A   + (size_t)(bm * 128) * D;
    const u16* Bb = WoT + (size_t)(bn * 128) * D;

    const int c0 = wave * 128 + ln;
    const int c1 = c0 + 64;
    const int r0 = c0 >> 2, o0 = (c0 & 3) * 8;
    const int r1 = c1 >> 2, o1 = (c1 & 3) * 8;

    f32x4 acc[4][4] = {};

    for (int k0 = 0; k0 < D; k0 += 32) {
        __syncthreads();
        llds16(Ab + (size_t)r0 * D + k0 + o0, &As[(wave * 2 + 0) * 512]);
        llds16(Ab + (size_t)r1 * D + k0 + o1, &As[(wave * 2 + 1) * 512]);
        llds16(Bb + (size_t)r0 * D + k0 + o0, &Bs[(wave * 2 + 0) * 512]);
        llds16(Bb + (size_t)r1 * D + k0 + o1, &Bs[(wave * 2 + 1) * 512]);
        __syncthreads();
        bf16x8 af[4], bfr[4];
        #pragma unroll
        for (int i = 0; i < 4; ++i)
            af[i] = *reinterpret_cast<const bf16x8*>(&As[(wm + i * 16 + ln15) * 32 + quad * 8]);
        #pragma unroll
        for (int j = 0; j < 4; ++j)
            bfr[j] = *reinterpret_cast<const bf16x8*>(&Bs[(wn + j * 16 + ln15) * 32 + quad * 8]);
        #pragma unroll
        for (int i = 0; i < 4; ++i)
            #pragma unroll
            for (int j = 0; j < 4; ++j)
                acc[i][j] = mfma16(af[i], bfr[j], acc[i][j]);
    }

    #pragma unroll
    for (int i = 0; i < 4; ++i)
        #pragma unroll
        for (int j = 0; j < 4; ++j)
            #pragma unroll
            for (int r = 0; r < 4; ++r) {
                int t   = bm * 128 + wm + i * 16 + quad * 4 + r;
                int col = bn * 128 + wn + j * 16 + ln15;
                out[(size_t)t * D + col] = acc[i][j][r] + bo[col];
            }
}

extern "C" void kernel_launch(void* const* d_in, const int* in_sizes, int n_in,
                              void* d_out, int out_size, void* d_ws, size_t ws_size,
                              hipStream_t stream) {
    const float* x  = (const float*)d_in[0];
    const float* Wq = (const float*)d_in[1];
    const float* Wk = (const float*)d_in[2];
    const float* Wv = (const float*)d_in[3];
    const float* Wo = (const float*)d_in[4];
    const float* bo = (const float*)d_in[5];
    float* out = (float*)d_out;
    u16* ws  = (u16*)d_ws;

    u16* WT   = ws;                                   // 4M u16  (8 MB)
    u16* xb   = WT + (size_t)4 * D * D;               // 8M u16  (16 MB)
    u16* qkvb = xb + (size_t)M * D;                   // slots: Q, K, Vt (48 MB)
    u16* kb   = qkvb + (size_t)M * D;
    u16* vtb  = qkvb + (size_t)2 * M * D;             // V written transposed here
    u16* attn = xb;                                   // xb dead after qkv_gemm128

    x_to_bf16   <<<dim3(M * D / (256 * 8)), 256, 0, stream>>>(x, xb);
    transpose_w <<<dim3(16, 16, 4), 256, 0, stream>>>(Wq, Wk, Wv, Wo, WT);
    qkv_gemm128 <<<dim3(64, 24),    256, 0, stream>>>(xb, WT, qkvb, vtb);
    attn_kernel <<<dim3(8, 64),     256, 0, stream>>>(qkvb, kb, vtb, attn);
    proj_gemm128<<<dim3(64, 8),     256, 0, stream>>>(attn, WT + (size_t)3 * D * D, bo, out);
}